// Round 4
// baseline (2106.158 us; speedup 1.0000x reference)
//
#include <hip/hip_runtime.h>

// MirrorAttention on MI355X (gfx950). Round 3: inputs/outputs are FP32 (per the
// reference's jnp.float32 and the harness dtype rule); internals stay bf16 MFMA.
// B=8, C=512, H=W=48 -> N=2304, MID=128.
//
// fold:  convert/fold all weights to bf16 ws copies (BN folded into Wa/Wv),
//        biases to f32.
// per direction, per batch:
//        fa_b = relu(WaE @ x_b + baE) ; q_b = relu(WvE @ xq_b + bvE)  [B fp32]
//        g_b  = WgE @ x_b + bg
//        P    = softmax_rows( scale * q_b^T @ fa_b )   [P bf16, in d_out o_h half]
//        omid_b = g_b @ P
// final: out = WfE @ omid + bf + x   [fp32 out, fp32 resid]  -- o_h final runs LAST
//        (it clobbers the P scratch region only after all P uses are complete).

typedef __attribute__((ext_vector_type(8))) short short8;
typedef __attribute__((ext_vector_type(4))) short short4_t;
typedef __attribute__((ext_vector_type(8))) __bf16 bf16x8;
typedef __attribute__((ext_vector_type(4))) float f32x4;

#define DEV __device__ __forceinline__

constexpr int BB = 8, CC = 512, MID = 128, NB = 2304;
constexpr float ATT_SCALE = 0.08838834764831845f;   // 128^-0.5
constexpr float RSQ = 0.9999950000374998f;          // 1/sqrt(1+1e-5)

DEV float bf2f(unsigned short u) {
    unsigned int x = ((unsigned int)u) << 16;
    return __builtin_bit_cast(float, x);
}
DEV unsigned short f2bf(float f) {   // round-to-nearest-even
    unsigned int x = __builtin_bit_cast(unsigned int, f);
    x += 0x7fffu + ((x >> 16) & 1u);
    return (unsigned short)(x >> 16);
}

// ---------------------------------------------------------------------------
// fold kernel: all fp32 weight inputs -> bf16 ws copies (BN folded), biases -> f32.
// biases (floats): [0:128]=baE [128:256]=bvE [256:384]=bgav [384:512]=bgah
//                  [512:1024]=bfav [1024:1536]=bfah
__global__ __launch_bounds__(256)
void fold_kernel(const float* __restrict__ Wa, const float* __restrict__ ba,
                 const float* __restrict__ ga, const float* __restrict__ ta,
                 const float* __restrict__ Wv, const float* __restrict__ bv,
                 const float* __restrict__ gv, const float* __restrict__ tv,
                 const float* __restrict__ Wgav, const float* __restrict__ bgav,
                 const float* __restrict__ Wgah, const float* __restrict__ bgah,
                 const float* __restrict__ Wfav, const float* __restrict__ bfav,
                 const float* __restrict__ Wfah, const float* __restrict__ bfah,
                 unsigned short* __restrict__ WaE, unsigned short* __restrict__ WvE,
                 unsigned short* __restrict__ WgavE, unsigned short* __restrict__ WgahE,
                 unsigned short* __restrict__ WfavE, unsigned short* __restrict__ WfahE,
                 float* __restrict__ biases)
{
    int idx = blockIdx.x * 256 + threadIdx.x;
    if (idx < 65536) {
        int m = idx >> 9;                  // row of [128][512]
        WaE[idx]   = f2bf(ga[m] * RSQ * Wa[idx]);
        WvE[idx]   = f2bf(gv[m] * RSQ * Wv[idx]);
        WgavE[idx] = f2bf(Wgav[idx]);
        WgahE[idx] = f2bf(Wgah[idx]);
        WfavE[idx] = f2bf(Wfav[idx]);      // [512][128] flat, same 65536 count
        WfahE[idx] = f2bf(Wfah[idx]);
    }
    if (idx < 128) {
        biases[idx]       = ba[idx] * ga[idx] * RSQ + ta[idx];
        biases[128 + idx] = bv[idx] * gv[idx] * RSQ + tv[idx];
        biases[256 + idx] = bgav[idx];
        biases[384 + idx] = bgah[idx];
    }
    if (idx < 512) {
        biases[512 + idx]  = bfav[idx];
        biases[1024 + idx] = bfah[idx];
    }
}

// ---------------------------------------------------------------------------
// Generic MFMA GEMM: OUT[m,n] = epilogue( sum_k A[m,k]*B[k,n] )
//   A is bf16 (ws). AT=false: A[Mdim][Kdim]; AT=true: A[Kdim][Mdim] (score q^T).
//   B[Kdim][Ndim]: bf16 ws if !BF32, fp32 d_in if BF32.
//   OUT: bf16 ws if !OF32, fp32 d_out if OF32.
//   EPI: 0 = acc*outscale; 1 = relu(acc+bias[m]); 2 = acc+bias[m];
//        3 = acc+bias[m]+resid[m,n] (resid fp32)
template<bool AT, int EPI, bool BF32, bool OF32>
__global__ __launch_bounds__(256)
void gemm_kernel(const unsigned short* __restrict__ A, long sAb,
                 const void* __restrict__ Bm, long sBb,
                 void* __restrict__ Out, long sOb,
                 const float* __restrict__ bias,
                 const float* __restrict__ resid, long sRb,
                 int Mdim, int Kdim, int Ndim, float outscale)
{
    constexpr int TM = 64, TN = 64, TK = 32, LD = TK + 8;
    __shared__ unsigned short As[TM * LD];
    __shared__ unsigned short Bs[TN * LD];

    const int tid  = threadIdx.x;
    const int lane = tid & 63;
    const int wave = tid >> 6;
    const int wm = wave >> 1, wn = wave & 1;
    const int m0 = blockIdx.y * TM, n0 = blockIdx.x * TN;
    const int z  = blockIdx.z;

    const unsigned short* Ab = A + (long)z * sAb;

    f32x4 acc[2][2] = {};

    const int ar = tid >> 2, ac = (tid & 3) * 8;   // row-major A staging
    const int tk = tid >> 3, tq = (tid & 7) * 8;   // K-major (transpose) staging
    const int lm = lane & 15, kq = (lane >> 4) * 8;

    for (int k0 = 0; k0 < Kdim; k0 += TK) {
        if constexpr (!AT) {
            short8 v = *(const short8*)(Ab + (long)(m0 + ar) * Kdim + (k0 + ac));
            *(short8*)(&As[ar * LD + ac]) = v;
        } else {
            short8 v = *(const short8*)(Ab + (long)(k0 + tk) * Mdim + (m0 + tq));
            #pragma unroll
            for (int i = 0; i < 8; i++) As[(tq + i) * LD + tk] = (unsigned short)v[i];
        }
        if constexpr (BF32) {
            const float* Bf = (const float*)Bm + (long)z * sBb;
            f32x4 a0 = *(const f32x4*)(Bf + (long)(k0 + tk) * Ndim + (n0 + tq));
            f32x4 a1 = *(const f32x4*)(Bf + (long)(k0 + tk) * Ndim + (n0 + tq) + 4);
            #pragma unroll
            for (int i = 0; i < 4; i++) Bs[(tq + i) * LD + tk]     = f2bf(a0[i]);
            #pragma unroll
            for (int i = 0; i < 4; i++) Bs[(tq + 4 + i) * LD + tk] = f2bf(a1[i]);
        } else {
            const unsigned short* Bu = (const unsigned short*)Bm + (long)z * sBb;
            short8 v = *(const short8*)(Bu + (long)(k0 + tk) * Ndim + (n0 + tq));
            #pragma unroll
            for (int i = 0; i < 8; i++) Bs[(tq + i) * LD + tk] = (unsigned short)v[i];
        }
        __syncthreads();

        bf16x8 afr[2], bfr[2];
        afr[0] = __builtin_bit_cast(bf16x8, *(const short8*)(&As[(wm * 32 + lm) * LD + kq]));
        afr[1] = __builtin_bit_cast(bf16x8, *(const short8*)(&As[(wm * 32 + 16 + lm) * LD + kq]));
        bfr[0] = __builtin_bit_cast(bf16x8, *(const short8*)(&Bs[(wn * 32 + lm) * LD + kq]));
        bfr[1] = __builtin_bit_cast(bf16x8, *(const short8*)(&Bs[(wn * 32 + 16 + lm) * LD + kq]));
        #pragma unroll
        for (int i = 0; i < 2; i++)
            #pragma unroll
            for (int j = 0; j < 2; j++)
                acc[i][j] = __builtin_amdgcn_mfma_f32_16x16x32_bf16(afr[i], bfr[j], acc[i][j], 0, 0, 0);
        __syncthreads();
    }

    const float* Rb = nullptr;
    if constexpr (EPI == 3) Rb = resid + (long)z * sRb;

    const int col = lane & 15, rb = (lane >> 4) * 4;
    #pragma unroll
    for (int i = 0; i < 2; i++) {
        #pragma unroll
        for (int j = 0; j < 2; j++) {
            const int mB = m0 + wm * 32 + i * 16 + rb;
            const int on = n0 + wn * 32 + j * 16 + col;
            #pragma unroll
            for (int r = 0; r < 4; r++) {
                const int m = mB + r;
                float v = acc[i][j][r];
                if constexpr (EPI == 0) {
                    v *= outscale;
                } else {
                    v += bias[m];
                    if constexpr (EPI == 1) v = fmaxf(v, 0.0f);
                    if constexpr (EPI == 3) v += Rb[(long)m * Ndim + on];
                }
                if constexpr (OF32) {
                    float* Of = (float*)Out + (long)z * sOb;
                    Of[(long)m * Ndim + on] = v;
                } else {
                    unsigned short* Ou = (unsigned short*)Out + (long)z * sOb;
                    Ou[(long)m * Ndim + on] = f2bf(v);
                }
            }
        }
    }
}

// ---------------------------------------------------------------------------
// In-place row softmax over P[rows][NB] (bf16), one wave per row (NB = 2304).
__global__ __launch_bounds__(256)
void softmax_rows(unsigned short* __restrict__ P)
{
    const int row  = blockIdx.x * 4 + (threadIdx.x >> 6);
    const int lane = threadIdx.x & 63;
    unsigned short* p = P + (long)row * NB;

    float vals[36];
    #pragma unroll
    for (int c = 0; c < 4; c++) {
        short8 v = *(const short8*)(p + c * 512 + lane * 8);
        #pragma unroll
        for (int e = 0; e < 8; e++) vals[c * 8 + e] = bf2f((unsigned short)v[e]);
    }
    {
        short4_t v = *(const short4_t*)(p + 2048 + lane * 4);
        #pragma unroll
        for (int e = 0; e < 4; e++) vals[32 + e] = bf2f((unsigned short)v[e]);
    }

    float mx = vals[0];
    #pragma unroll
    for (int i = 1; i < 36; i++) mx = fmaxf(mx, vals[i]);
    #pragma unroll
    for (int off = 32; off > 0; off >>= 1) mx = fmaxf(mx, __shfl_xor(mx, off, 64));

    float s = 0.f;
    #pragma unroll
    for (int i = 0; i < 36; i++) { vals[i] = __expf(vals[i] - mx); s += vals[i]; }
    #pragma unroll
    for (int off = 32; off > 0; off >>= 1) s += __shfl_xor(s, off, 64);
    const float rs = 1.0f / s;

    #pragma unroll
    for (int c = 0; c < 4; c++) {
        short8 w;
        #pragma unroll
        for (int e = 0; e < 8; e++) w[e] = (short)f2bf(vals[c * 8 + e] * rs);
        *(short8*)(p + c * 512 + lane * 8) = w;
    }
    {
        short4_t w;
        #pragma unroll
        for (int e = 0; e < 4; e++) w[e] = (short)f2bf(vals[32 + e] * rs);
        *(short4_t*)(p + 2048 + lane * 4) = w;
    }
}

// ---------------------------------------------------------------------------
extern "C" void kernel_launch(void* const* d_in, const int* in_sizes, int n_in,
                              void* d_out, int out_size, void* d_ws, size_t ws_size,
                              hipStream_t stream)
{
    const float* x    = (const float*)d_in[0];
    const float* x_h  = (const float*)d_in[1];
    const float* x_v  = (const float*)d_in[2];
    const float* Wa   = (const float*)d_in[3];
    const float* ba   = (const float*)d_in[4];
    const float* ga   = (const float*)d_in[5];
    const float* ta   = (const float*)d_in[6];
    const float* Wv   = (const float*)d_in[7];
    const float* bv   = (const float*)d_in[8];
    const float* gv   = (const float*)d_in[9];
    const float* tv   = (const float*)d_in[10];
    const float* Wgav = (const float*)d_in[11];
    const float* bgav = (const float*)d_in[12];
    const float* Wgah = (const float*)d_in[13];
    const float* bgah = (const float*)d_in[14];
    const float* Wfav = (const float*)d_in[15];
    const float* bfav = (const float*)d_in[16];
    const float* Wfah = (const float*)d_in[17];
    const float* bfah = (const float*)d_in[18];
    float* out = (float*)d_out;

    const long sX = (long)CC * NB;        // 1179648 elements
    const long sF = (long)MID * NB;       // 294912
    const long HALF = (long)BB * sX;      // o_h at out[0], o_v at out[HALF] (floats)

    // ws layout (ushort elements): total 3,640,320 shorts = 7,280,640 bytes
    constexpr size_t WS_NEED = 7280640;
    if (ws_size < WS_NEED) return;        // diagnostic: output stays memset-0 -> finite absmax

    unsigned short* ws = (unsigned short*)d_ws;
    unsigned short* WaE   = ws;                 //  65536
    unsigned short* WvE   = ws + 65536;
    unsigned short* WgavE = ws + 131072;
    unsigned short* WgahE = ws + 196608;
    unsigned short* WfavE = ws + 262144;
    unsigned short* WfahE = ws + 327680;
    float* biases = (float*)(ws + 393216);      // 1536 floats (3072 shorts)
    unsigned short* fab  = ws + 396288;         // 294912
    unsigned short* qb   = ws + 691200;         // 294912
    unsigned short* gb   = ws + 986112;         // 294912
    unsigned short* omid = ws + 1281024;        // 2359296
    // end: 3,640,320 shorts

    // P scratch (bf16, 2304*2304 = 5,308,416 shorts = 10.6 MB) lives in d_out's
    // o_h half (fp32, 37.7 MB); the o_h final GEMM (last kernel) overwrites it.
    unsigned short* Pb = (unsigned short*)d_out;

    float* baE   = biases;
    float* bvE   = biases + 128;
    float* bgavF = biases + 256;
    float* bgahF = biases + 384;
    float* bfavF = biases + 512;
    float* bfahF = biases + 1024;

    fold_kernel<<<256, 256, 0, stream>>>(Wa, ba, ga, ta, Wv, bv, gv, tv,
                                         Wgav, bgav, Wgah, bgah, Wfav, bfav, Wfah, bfah,
                                         WaE, WvE, WgavE, WgahE, WfavE, WfahE, biases);

    const dim3 blk(256);

    // ---- direction v (queries from x_v; values via Wgav) -> o_v at out+HALF ----
    for (int b = 0; b < BB; b++) {
        const float* xb  = x   + (long)b * sX;
        const float* xqb = x_v + (long)b * sX;
        gemm_kernel<false,1,true,false><<<dim3(36,2,1), blk, 0, stream>>>(WaE,   0, xb,  0, fab, 0, baE,   nullptr, 0, MID, CC, NB, 1.f);
        gemm_kernel<false,1,true,false><<<dim3(36,2,1), blk, 0, stream>>>(WvE,   0, xqb, 0, qb,  0, bvE,   nullptr, 0, MID, CC, NB, 1.f);
        gemm_kernel<false,2,true,false><<<dim3(36,2,1), blk, 0, stream>>>(WgavE, 0, xb,  0, gb,  0, bgavF, nullptr, 0, MID, CC, NB, 1.f);
        gemm_kernel<true,0,false,false><<<dim3(36,36,1), blk, 0, stream>>>(qb, 0, fab, 0, Pb, 0, nullptr, nullptr, 0, NB, MID, NB, ATT_SCALE);
        softmax_rows<<<NB / 4, blk, 0, stream>>>(Pb);
        gemm_kernel<false,0,false,false><<<dim3(36,2,1), blk, 0, stream>>>(gb, 0, Pb, 0, omid + (long)b * sF, 0, nullptr, nullptr, 0, MID, NB, NB, 1.f);
    }
    gemm_kernel<false,3,false,true><<<dim3(36,8,8), blk, 0, stream>>>(WfavE, 0, omid, sF, out + HALF, sX, bfavF, x, sX, CC, MID, NB, 1.f);

    // ---- direction h (queries from x_h; values via Wgah) -> o_h at out[0] ----
    for (int b = 0; b < BB; b++) {
        const float* xb  = x   + (long)b * sX;
        const float* xqb = x_h + (long)b * sX;
        gemm_kernel<false,1,true,false><<<dim3(36,2,1), blk, 0, stream>>>(WaE,   0, xb,  0, fab, 0, baE,   nullptr, 0, MID, CC, NB, 1.f);
        gemm_kernel<false,1,true,false><<<dim3(36,2,1), blk, 0, stream>>>(WvE,   0, xqb, 0, qb,  0, bvE,   nullptr, 0, MID, CC, NB, 1.f);
        gemm_kernel<false,2,true,false><<<dim3(36,2,1), blk, 0, stream>>>(WgahE, 0, xb,  0, gb,  0, bgahF, nullptr, 0, MID, CC, NB, 1.f);
        gemm_kernel<true,0,false,false><<<dim3(36,36,1), blk, 0, stream>>>(qb, 0, fab, 0, Pb, 0, nullptr, nullptr, 0, NB, MID, NB, ATT_SCALE);
        softmax_rows<<<NB / 4, blk, 0, stream>>>(Pb);
        gemm_kernel<false,0,false,false><<<dim3(36,2,1), blk, 0, stream>>>(gb, 0, Pb, 0, omid + (long)b * sF, 0, nullptr, nullptr, 0, MID, NB, NB, 1.f);
    }
    // LAST kernel: writes o_h half (fp32), clobbering Pb scratch after all P uses.
    gemm_kernel<false,3,false,true><<<dim3(36,8,8), blk, 0, stream>>>(WfahE, 0, omid, sF, out, sX, bfahF, x, sX, CC, MID, NB, 1.f);

    (void)in_sizes; (void)n_in; (void)out_size;
}

// Round 5
// 670.923 us; speedup vs baseline: 3.1392x; 3.1392x over previous
//
#include <hip/hip_runtime.h>

// MirrorAttention on MI355X (gfx950). Round 4: full z=8 batching (kills the
// 72-block latency-bound PV GEMMs: 848us = 40% of R3 runtime at 2.9% occupancy),
// plus stats-only softmax (m, 1/l per row) with exp folded into PV's B-staging
// (saves one 85MB P write + read per direction).
// Inputs/outputs fp32; internals bf16 MFMA. B=8, C=512, N=2304, MID=128.
//
// Big path (ws >= 114.2 MB):
//   fold -> 5 batched projections (z=8) ->
//   per direction: score(z=8) -> P raw S (bf16); stats; PV(z=8, exp on the fly);
//                  final(z=8) -> fp32 out half.   o_h final runs LAST.
// Fallback (ws < 114.2 MB): exact Round-3 per-batch path (passed at 2106 us).

typedef __attribute__((ext_vector_type(8))) short short8;
typedef __attribute__((ext_vector_type(4))) short short4_t;
typedef __attribute__((ext_vector_type(8))) __bf16 bf16x8;
typedef __attribute__((ext_vector_type(4))) float f32x4;

#define DEV __device__ __forceinline__

constexpr int BB = 8, CC = 512, MID = 128, NB = 2304;
constexpr float ATT_SCALE = 0.08838834764831845f;   // 128^-0.5
constexpr float RSQ = 0.9999950000374998f;          // 1/sqrt(1+1e-5)

DEV float bf2f(unsigned short u) {
    unsigned int x = ((unsigned int)u) << 16;
    return __builtin_bit_cast(float, x);
}
DEV unsigned short f2bf(float f) {   // round-to-nearest-even
    unsigned int x = __builtin_bit_cast(unsigned int, f);
    x += 0x7fffu + ((x >> 16) & 1u);
    return (unsigned short)(x >> 16);
}

// ---------------------------------------------------------------------------
// fold kernel: fp32 weights -> bf16 ws copies (BN folded), biases -> f32.
// biases (floats): [0:128]=baE [128:256]=bvE [256:384]=bgav [384:512]=bgah
//                  [512:1024]=bfav [1024:1536]=bfah
__global__ __launch_bounds__(256)
void fold_kernel(const float* __restrict__ Wa, const float* __restrict__ ba,
                 const float* __restrict__ ga, const float* __restrict__ ta,
                 const float* __restrict__ Wv, const float* __restrict__ bv,
                 const float* __restrict__ gv, const float* __restrict__ tv,
                 const float* __restrict__ Wgav, const float* __restrict__ bgav,
                 const float* __restrict__ Wgah, const float* __restrict__ bgah,
                 const float* __restrict__ Wfav, const float* __restrict__ bfav,
                 const float* __restrict__ Wfah, const float* __restrict__ bfah,
                 unsigned short* __restrict__ WaE, unsigned short* __restrict__ WvE,
                 unsigned short* __restrict__ WgavE, unsigned short* __restrict__ WgahE,
                 unsigned short* __restrict__ WfavE, unsigned short* __restrict__ WfahE,
                 float* __restrict__ biases)
{
    int idx = blockIdx.x * 256 + threadIdx.x;
    if (idx < 65536) {
        int m = idx >> 9;                  // row of [128][512]
        WaE[idx]   = f2bf(ga[m] * RSQ * Wa[idx]);
        WvE[idx]   = f2bf(gv[m] * RSQ * Wv[idx]);
        WgavE[idx] = f2bf(Wgav[idx]);
        WgahE[idx] = f2bf(Wgah[idx]);
        WfavE[idx] = f2bf(Wfav[idx]);      // [512][128] flat, same 65536 count
        WfahE[idx] = f2bf(Wfah[idx]);
    }
    if (idx < 128) {
        biases[idx]       = ba[idx] * ga[idx] * RSQ + ta[idx];
        biases[128 + idx] = bv[idx] * gv[idx] * RSQ + tv[idx];
        biases[256 + idx] = bgav[idx];
        biases[384 + idx] = bgah[idx];
    }
    if (idx < 512) {
        biases[512 + idx]  = bfav[idx];
        biases[1024 + idx] = bfah[idx];
    }
}

// ---------------------------------------------------------------------------
// Generic MFMA GEMM: OUT[m,n] = epilogue( sum_k A[m,k]*B[k,n] )
//   A bf16. AT=false: A[Mdim][Kdim]; AT=true: A[Kdim][Mdim] (score q^T).
//   B[Kdim][Ndim]: fp32 (BF32) or bf16. EXPB: B holds raw scaled S; staging
//   applies exp(S - m_k) * rinv_k from stats[2*(zoff+k)] (PV on-the-fly softmax).
//   OUT: fp32 (OF32) or bf16.
//   EPI: 0 acc*outscale; 1 relu(acc+bias[m]); 2 acc+bias[m]; 3 acc+bias[m]+resid[m,n]
template<bool AT, int EPI, bool BF32, bool OF32, bool EXPB>
__global__ __launch_bounds__(256)
void gemm_kernel(const unsigned short* __restrict__ A, long sAb,
                 const void* __restrict__ Bm, long sBb,
                 void* __restrict__ Out, long sOb,
                 const float* __restrict__ bias,
                 const float* __restrict__ resid, long sRb,
                 const float* __restrict__ stats,
                 int Mdim, int Kdim, int Ndim, float outscale)
{
    constexpr int TM = 64, TN = 64, TK = 32, LD = TK + 8;
    __shared__ unsigned short As[TM * LD];
    __shared__ unsigned short Bs[TN * LD];

    const int tid  = threadIdx.x;
    const int lane = tid & 63;
    const int wave = tid >> 6;
    const int wm = wave >> 1, wn = wave & 1;
    const int m0 = blockIdx.y * TM, n0 = blockIdx.x * TN;
    const int z  = blockIdx.z;

    const unsigned short* Ab = A + (long)z * sAb;

    f32x4 acc[2][2] = {};

    const int ar = tid >> 2, ac = (tid & 3) * 8;   // row-major A staging
    const int tk = tid >> 3, tq = (tid & 7) * 8;   // K-major (transpose) staging
    const int lm = lane & 15, kq = (lane >> 4) * 8;

    for (int k0 = 0; k0 < Kdim; k0 += TK) {
        if constexpr (!AT) {
            short8 v = *(const short8*)(Ab + (long)(m0 + ar) * Kdim + (k0 + ac));
            *(short8*)(&As[ar * LD + ac]) = v;
        } else {
            short8 v = *(const short8*)(Ab + (long)(k0 + tk) * Mdim + (m0 + tq));
            #pragma unroll
            for (int i = 0; i < 8; i++) As[(tq + i) * LD + tk] = (unsigned short)v[i];
        }
        if constexpr (BF32) {
            const float* Bf = (const float*)Bm + (long)z * sBb;
            f32x4 a0 = *(const f32x4*)(Bf + (long)(k0 + tk) * Ndim + (n0 + tq));
            f32x4 a1 = *(const f32x4*)(Bf + (long)(k0 + tk) * Ndim + (n0 + tq) + 4);
            #pragma unroll
            for (int i = 0; i < 4; i++) Bs[(tq + i) * LD + tk]     = f2bf(a0[i]);
            #pragma unroll
            for (int i = 0; i < 4; i++) Bs[(tq + 4 + i) * LD + tk] = f2bf(a1[i]);
        } else {
            const unsigned short* Bu = (const unsigned short*)Bm + (long)z * sBb;
            short8 v = *(const short8*)(Bu + (long)(k0 + tk) * Ndim + (n0 + tq));
            if constexpr (EXPB) {
                const long krow = (long)z * NB + (k0 + tk);
                const float mrow = stats[2 * krow];
                const float rinv = stats[2 * krow + 1];
                #pragma unroll
                for (int i = 0; i < 8; i++)
                    Bs[(tq + i) * LD + tk] =
                        f2bf(__expf(bf2f((unsigned short)v[i]) - mrow) * rinv);
            } else {
                #pragma unroll
                for (int i = 0; i < 8; i++) Bs[(tq + i) * LD + tk] = (unsigned short)v[i];
            }
        }
        __syncthreads();

        bf16x8 afr[2], bfr[2];
        afr[0] = __builtin_bit_cast(bf16x8, *(const short8*)(&As[(wm * 32 + lm) * LD + kq]));
        afr[1] = __builtin_bit_cast(bf16x8, *(const short8*)(&As[(wm * 32 + 16 + lm) * LD + kq]));
        bfr[0] = __builtin_bit_cast(bf16x8, *(const short8*)(&Bs[(wn * 32 + lm) * LD + kq]));
        bfr[1] = __builtin_bit_cast(bf16x8, *(const short8*)(&Bs[(wn * 32 + 16 + lm) * LD + kq]));
        #pragma unroll
        for (int i = 0; i < 2; i++)
            #pragma unroll
            for (int j = 0; j < 2; j++)
                acc[i][j] = __builtin_amdgcn_mfma_f32_16x16x32_bf16(afr[i], bfr[j], acc[i][j], 0, 0, 0);
        __syncthreads();
    }

    const float* Rb = nullptr;
    if constexpr (EPI == 3) Rb = resid + (long)z * sRb;

    const int col = lane & 15, rb = (lane >> 4) * 4;
    #pragma unroll
    for (int i = 0; i < 2; i++) {
        #pragma unroll
        for (int j = 0; j < 2; j++) {
            const int mB = m0 + wm * 32 + i * 16 + rb;
            const int on = n0 + wn * 32 + j * 16 + col;
            #pragma unroll
            for (int r = 0; r < 4; r++) {
                const int m = mB + r;
                float v = acc[i][j][r];
                if constexpr (EPI == 0) {
                    v *= outscale;
                } else {
                    v += bias[m];
                    if constexpr (EPI == 1) v = fmaxf(v, 0.0f);
                    if constexpr (EPI == 3) v += Rb[(long)m * Ndim + on];
                }
                if constexpr (OF32) {
                    float* Of = (float*)Out + (long)z * sOb;
                    Of[(long)m * Ndim + on] = v;
                } else {
                    unsigned short* Ou = (unsigned short*)Out + (long)z * sOb;
                    Ou[(long)m * Ndim + on] = f2bf(v);
                }
            }
        }
    }
}

// ---------------------------------------------------------------------------
// Row stats over S[rows][NB] (bf16 raw scaled scores): stats[row] = {max, 1/sum}.
// One wave per row; rows contiguous across batches (P batches contiguous).
__global__ __launch_bounds__(256)
void softmax_stats(const unsigned short* __restrict__ P, float* __restrict__ stats)
{
    const int row  = blockIdx.x * 4 + (threadIdx.x >> 6);
    const int lane = threadIdx.x & 63;
    const unsigned short* p = P + (long)row * NB;

    float vals[36];
    #pragma unroll
    for (int c = 0; c < 4; c++) {
        short8 v = *(const short8*)(p + c * 512 + lane * 8);
        #pragma unroll
        for (int e = 0; e < 8; e++) vals[c * 8 + e] = bf2f((unsigned short)v[e]);
    }
    {
        short4_t v = *(const short4_t*)(p + 2048 + lane * 4);
        #pragma unroll
        for (int e = 0; e < 4; e++) vals[32 + e] = bf2f((unsigned short)v[e]);
    }

    float mx = vals[0];
    #pragma unroll
    for (int i = 1; i < 36; i++) mx = fmaxf(mx, vals[i]);
    #pragma unroll
    for (int off = 32; off > 0; off >>= 1) mx = fmaxf(mx, __shfl_xor(mx, off, 64));

    float s = 0.f;
    #pragma unroll
    for (int i = 0; i < 36; i++) s += __expf(vals[i] - mx);
    #pragma unroll
    for (int off = 32; off > 0; off >>= 1) s += __shfl_xor(s, off, 64);

    if (lane == 0) {
        stats[2 * (long)row]     = mx;
        stats[2 * (long)row + 1] = 1.0f / s;
    }
}

// ---------------------------------------------------------------------------
// In-place row softmax (fallback path only).
__global__ __launch_bounds__(256)
void softmax_rows(unsigned short* __restrict__ P)
{
    const int row  = blockIdx.x * 4 + (threadIdx.x >> 6);
    const int lane = threadIdx.x & 63;
    unsigned short* p = P + (long)row * NB;

    float vals[36];
    #pragma unroll
    for (int c = 0; c < 4; c++) {
        short8 v = *(const short8*)(p + c * 512 + lane * 8);
        #pragma unroll
        for (int e = 0; e < 8; e++) vals[c * 8 + e] = bf2f((unsigned short)v[e]);
    }
    {
        short4_t v = *(const short4_t*)(p + 2048 + lane * 4);
        #pragma unroll
        for (int e = 0; e < 4; e++) vals[32 + e] = bf2f((unsigned short)v[e]);
    }

    float mx = vals[0];
    #pragma unroll
    for (int i = 1; i < 36; i++) mx = fmaxf(mx, vals[i]);
    #pragma unroll
    for (int off = 32; off > 0; off >>= 1) mx = fmaxf(mx, __shfl_xor(mx, off, 64));

    float s = 0.f;
    #pragma unroll
    for (int i = 0; i < 36; i++) { vals[i] = __expf(vals[i] - mx); s += vals[i]; }
    #pragma unroll
    for (int off = 32; off > 0; off >>= 1) s += __shfl_xor(s, off, 64);
    const float rs = 1.0f / s;

    #pragma unroll
    for (int c = 0; c < 4; c++) {
        short8 w;
        #pragma unroll
        for (int e = 0; e < 8; e++) w[e] = (short)f2bf(vals[c * 8 + e] * rs);
        *(short8*)(p + c * 512 + lane * 8) = w;
    }
    {
        short4_t w;
        #pragma unroll
        for (int e = 0; e < 4; e++) w[e] = (short)f2bf(vals[32 + e] * rs);
        *(short4_t*)(p + 2048 + lane * 4) = w;
    }
}

// ---------------------------------------------------------------------------
extern "C" void kernel_launch(void* const* d_in, const int* in_sizes, int n_in,
                              void* d_out, int out_size, void* d_ws, size_t ws_size,
                              hipStream_t stream)
{
    const float* x    = (const float*)d_in[0];
    const float* x_h  = (const float*)d_in[1];
    const float* x_v  = (const float*)d_in[2];
    const float* Wa   = (const float*)d_in[3];
    const float* ba   = (const float*)d_in[4];
    const float* ga   = (const float*)d_in[5];
    const float* ta   = (const float*)d_in[6];
    const float* Wv   = (const float*)d_in[7];
    const float* bv   = (const float*)d_in[8];
    const float* gv   = (const float*)d_in[9];
    const float* tv   = (const float*)d_in[10];
    const float* Wgav = (const float*)d_in[11];
    const float* bgav = (const float*)d_in[12];
    const float* Wgah = (const float*)d_in[13];
    const float* bgah = (const float*)d_in[14];
    const float* Wfav = (const float*)d_in[15];
    const float* bfav = (const float*)d_in[16];
    const float* Wfah = (const float*)d_in[17];
    const float* bfah = (const float*)d_in[18];
    float* out = (float*)d_out;

    const long sX = (long)CC * NB;        // 1179648 elements
    const long sF = (long)MID * NB;       // 294912
    const long sP = (long)NB * NB;        // 5308416
    const long HALF = (long)BB * sX;      // o_h at out[0], o_v at out[HALF] (floats)

    const dim3 blk(256);
    unsigned short* ws = (unsigned short*)d_ws;

    // ---- big-path ws layout (shorts), total 57,093,120 shorts = 114,186,240 B
    constexpr size_t WS_BIG = 114186240ull;

    if (ws_size >= WS_BIG) {
        unsigned short* WaE   = ws;
        unsigned short* WvE   = ws + 65536;
        unsigned short* WgavE = ws + 131072;
        unsigned short* WgahE = ws + 196608;
        unsigned short* WfavE = ws + 262144;
        unsigned short* WfahE = ws + 327680;
        float* biases = (float*)(ws + 393216);     // 1536 floats -> ends 396288
        float* stats  = (float*)(ws + 396288);     // 8*2304*2 floats -> ends 470016
        unsigned short* fa   = ws + 470016;
        unsigned short* fv   = ws + 2829312;
        unsigned short* fh   = ws + 5188608;
        unsigned short* gav  = ws + 7547904;
        unsigned short* gah  = ws + 9907200;
        unsigned short* omid = ws + 12266496;
        unsigned short* P    = ws + 14625792;      // 8*5308416 shorts

        float* baE   = biases;
        float* bvE   = biases + 128;
        float* bgavF = biases + 256;
        float* bgahF = biases + 384;
        float* bfavF = biases + 512;
        float* bfahF = biases + 1024;

        fold_kernel<<<256, 256, 0, stream>>>(Wa, ba, ga, ta, Wv, bv, gv, tv,
                                             Wgav, bgav, Wgah, bgah, Wfav, bfav, Wfah, bfah,
                                             WaE, WvE, WgavE, WgahE, WfavE, WfahE, biases);

        // batched projections (z=8): M=128, K=512, N=2304
        gemm_kernel<false,1,true,false,false><<<dim3(36,2,8), blk, 0, stream>>>(WaE,   0, x,   sX, fa,  sF, baE,   nullptr, 0, nullptr, MID, CC, NB, 1.f);
        gemm_kernel<false,1,true,false,false><<<dim3(36,2,8), blk, 0, stream>>>(WvE,   0, x_v, sX, fv,  sF, bvE,   nullptr, 0, nullptr, MID, CC, NB, 1.f);
        gemm_kernel<false,1,true,false,false><<<dim3(36,2,8), blk, 0, stream>>>(WvE,   0, x_h, sX, fh,  sF, bvE,   nullptr, 0, nullptr, MID, CC, NB, 1.f);
        gemm_kernel<false,2,true,false,false><<<dim3(36,2,8), blk, 0, stream>>>(WgavE, 0, x,   sX, gav, sF, bgavF, nullptr, 0, nullptr, MID, CC, NB, 1.f);
        gemm_kernel<false,2,true,false,false><<<dim3(36,2,8), blk, 0, stream>>>(WgahE, 0, x,   sX, gah, sF, bgahF, nullptr, 0, nullptr, MID, CC, NB, 1.f);

        // ---- direction v -> o_v at out+HALF ----
        gemm_kernel<true,0,false,false,false><<<dim3(36,36,8), blk, 0, stream>>>(fv, sF, fa, sF, P, sP, nullptr, nullptr, 0, nullptr, NB, MID, NB, ATT_SCALE);
        softmax_stats<<<BB * NB / 4, blk, 0, stream>>>(P, stats);
        gemm_kernel<false,0,false,false,true><<<dim3(36,2,8), blk, 0, stream>>>(gav, sF, P, sP, omid, sF, nullptr, nullptr, 0, stats, MID, NB, NB, 1.f);
        gemm_kernel<false,3,false,true,false><<<dim3(36,8,8), blk, 0, stream>>>(WfavE, 0, omid, sF, out + HALF, sX, bfavF, x, sX, nullptr, CC, MID, NB, 1.f);

        // ---- direction h -> o_h at out[0] ----
        gemm_kernel<true,0,false,false,false><<<dim3(36,36,8), blk, 0, stream>>>(fh, sF, fa, sF, P, sP, nullptr, nullptr, 0, nullptr, NB, MID, NB, ATT_SCALE);
        softmax_stats<<<BB * NB / 4, blk, 0, stream>>>(P, stats);
        gemm_kernel<false,0,false,false,true><<<dim3(36,2,8), blk, 0, stream>>>(gah, sF, P, sP, omid, sF, nullptr, nullptr, 0, stats, MID, NB, NB, 1.f);
        gemm_kernel<false,3,false,true,false><<<dim3(36,8,8), blk, 0, stream>>>(WfahE, 0, omid, sF, out, sX, bfahF, x, sX, nullptr, CC, MID, NB, 1.f);

        return;
    }

    // ---------------- fallback: exact Round-3 per-batch path ----------------
    constexpr size_t WS_NEED = 7280640;
    if (ws_size < WS_NEED) return;

    unsigned short* WaE   = ws;
    unsigned short* WvE   = ws + 65536;
    unsigned short* WgavE = ws + 131072;
    unsigned short* WgahE = ws + 196608;
    unsigned short* WfavE = ws + 262144;
    unsigned short* WfahE = ws + 327680;
    float* biases = (float*)(ws + 393216);
    unsigned short* fab  = ws + 396288;
    unsigned short* qb   = ws + 691200;
    unsigned short* gb   = ws + 986112;
    unsigned short* omid = ws + 1281024;
    unsigned short* Pb = (unsigned short*)d_out;

    float* baE   = biases;
    float* bvE   = biases + 128;
    float* bgavF = biases + 256;
    float* bgahF = biases + 384;
    float* bfavF = biases + 512;
    float* bfahF = biases + 1024;

    fold_kernel<<<256, 256, 0, stream>>>(Wa, ba, ga, ta, Wv, bv, gv, tv,
                                         Wgav, bgav, Wgah, bgah, Wfav, bfav, Wfah, bfah,
                                         WaE, WvE, WgavE, WgahE, WfavE, WfahE, biases);

    for (int b = 0; b < BB; b++) {
        const float* xb  = x   + (long)b * sX;
        const float* xqb = x_v + (long)b * sX;
        gemm_kernel<false,1,true,false,false><<<dim3(36,2,1), blk, 0, stream>>>(WaE,   0, xb,  0, fab, 0, baE,   nullptr, 0, nullptr, MID, CC, NB, 1.f);
        gemm_kernel<false,1,true,false,false><<<dim3(36,2,1), blk, 0, stream>>>(WvE,   0, xqb, 0, qb,  0, bvE,   nullptr, 0, nullptr, MID, CC, NB, 1.f);
        gemm_kernel<false,2,true,false,false><<<dim3(36,2,1), blk, 0, stream>>>(WgavE, 0, xb,  0, gb,  0, bgavF, nullptr, 0, nullptr, MID, CC, NB, 1.f);
        gemm_kernel<true,0,false,false,false><<<dim3(36,36,1), blk, 0, stream>>>(qb, 0, fab, 0, Pb, 0, nullptr, nullptr, 0, nullptr, NB, MID, NB, ATT_SCALE);
        softmax_rows<<<NB / 4, blk, 0, stream>>>(Pb);
        gemm_kernel<false,0,false,false,false><<<dim3(36,2,1), blk, 0, stream>>>(gb, 0, Pb, 0, omid + (long)b * sF, 0, nullptr, nullptr, 0, nullptr, MID, NB, NB, 1.f);
    }
    gemm_kernel<false,3,false,true,false><<<dim3(36,8,8), blk, 0, stream>>>(WfavE, 0, omid, sF, out + HALF, sX, bfavF, x, sX, nullptr, CC, MID, NB, 1.f);

    for (int b = 0; b < BB; b++) {
        const float* xb  = x   + (long)b * sX;
        const float* xqb = x_h + (long)b * sX;
        gemm_kernel<false,1,true,false,false><<<dim3(36,2,1), blk, 0, stream>>>(WaE,   0, xb,  0, fab, 0, baE,   nullptr, 0, nullptr, MID, CC, NB, 1.f);
        gemm_kernel<false,1,true,false,false><<<dim3(36,2,1), blk, 0, stream>>>(WvE,   0, xqb, 0, qb,  0, bvE,   nullptr, 0, nullptr, MID, CC, NB, 1.f);
        gemm_kernel<false,2,true,false,false><<<dim3(36,2,1), blk, 0, stream>>>(WgahE, 0, xb,  0, gb,  0, bgahF, nullptr, 0, nullptr, MID, CC, NB, 1.f);
        gemm_kernel<true,0,false,false,false><<<dim3(36,36,1), blk, 0, stream>>>(qb, 0, fab, 0, Pb, 0, nullptr, nullptr, 0, nullptr, NB, MID, NB, ATT_SCALE);
        softmax_rows<<<NB / 4, blk, 0, stream>>>(Pb);
        gemm_kernel<false,0,false,false,false><<<dim3(36,2,1), blk, 0, stream>>>(gb, 0, Pb, 0, omid + (long)b * sF, 0, nullptr, nullptr, 0, nullptr, MID, NB, NB, 1.f);
    }
    gemm_kernel<false,3,false,true,false><<<dim3(36,8,8), blk, 0, stream>>>(WfahE, 0, omid, sF, out, sX, bfahF, x, sX, nullptr, CC, MID, NB, 1.f);

    (void)in_sizes; (void)n_in; (void)out_size;
}